// Round 1
// baseline (109.685 us; speedup 1.0000x reference)
//
#include <hip/hip_runtime.h>

typedef unsigned int u32;
typedef short short8 __attribute__((ext_vector_type(8)));
typedef float f32x4 __attribute__((ext_vector_type(4)));
typedef float f32x16 __attribute__((ext_vector_type(16)));
typedef u32 u32x4 __attribute__((ext_vector_type(4)));

// ---------------- ws layout (u32 units) ----------------
// [0,      65536)  bf16-packed tables [16][4096] (lo=emb0, hi=emb1)
// [65536,  75776)  weight frags, frag-major: per (layer,nt,ks): 64 lanes x 4 u32
// [75776,  76224)  bias f32 [7][64] (zero padded)
#define WS_WT   65536
#define WS_BIAS 75776
#define WS_TOTAL_U32 76224
// frag bases (u32, relative to WS_WT == LDS index 0)
// L0:0  L1:1024  L2:3072  L3:4096  L4:5120  L5:7168  L6:9216   (end 10240)
// LDS: sm[10688] u32 = 42752 B.  During hash: sm[0..4096)=tblA, sm[4096..8192)=tblB.
// After hash: sm[0..10240)=weight frags, sm[10240..10688)=bias f32.

__device__ __forceinline__ u32 pkbf(float a, float b){
    u32 r; asm("v_cvt_pk_bf16_f32 %0, %1, %2" : "=v"(r) : "v"(a), "v"(b)); return r;
}
__device__ __forceinline__ void pswap(u32 &a, u32 &b){
    // swaps row1 of a with row0 of b: a_new[32+i]=b_old[i]; b_new[i]=a_old[32+i]
    asm("v_permlane32_swap_b32 %0, %1" : "+v"(a), "+v"(b));
}
__device__ __forceinline__ float lo16(u32 u){ return __uint_as_float(u << 16); }
__device__ __forceinline__ float hi16(u32 u){ return __uint_as_float(u & 0xffff0000u); }
__device__ __forceinline__ short8 mkfrag(u32 a, u32 b, u32 c, u32 d){
    u32x4 t = {a,b,c,d}; return __builtin_bit_cast(short8, t);
}
#define MFMA __builtin_amdgcn_mfma_f32_32x32x16_bf16

// ============================ prep kernel ============================
__global__ void prep_kernel(const float* __restrict__ tables,
    const float* __restrict__ dW0, const float* __restrict__ dW1, const float* __restrict__ dW2,
    const float* __restrict__ cW0, const float* __restrict__ cW1, const float* __restrict__ cW2,
    const float* __restrict__ cW3,
    const float* __restrict__ db0, const float* __restrict__ db1, const float* __restrict__ db2,
    const float* __restrict__ cb0, const float* __restrict__ cb1, const float* __restrict__ cb2,
    const float* __restrict__ cb3,
    u32* __restrict__ ws)
{
    int gid = blockIdx.x * 256 + threadIdx.x;
    if (gid < 65536){                       // tables -> bf16 pairs
        const float* t = tables + gid * 2;  // [16][4096][2] flat
        ws[gid] = pkbf(t[0], t[1]);
        return;
    }
    int wi = gid - 65536;
    if (wi < 10240){                        // weights -> frag-major bf16
        const float* src; int Nsrc, Kv, Nv, KS, rel;
        if      (wi < 1024){ src=dW0; Nsrc=64; Kv=32; Nv=64; KS=2; rel=wi;      }
        else if (wi < 3072){ src=dW1; Nsrc=64; Kv=64; Nv=64; KS=4; rel=wi-1024; }
        else if (wi < 4096){ src=dW2; Nsrc=16; Kv=64; Nv=16; KS=4; rel=wi-3072; }
        else if (wi < 5120){ src=cW0; Nsrc=64; Kv=16; Nv=64; KS=2; rel=wi-4096; }
        else if (wi < 7168){ src=cW1; Nsrc=64; Kv=64; Nv=64; KS=4; rel=wi-5120; }
        else if (wi < 9216){ src=cW2; Nsrc=64; Kv=64; Nv=64; KS=4; rel=wi-7168; }
        else               { src=cW3; Nsrc=3;  Kv=64; Nv=3;  KS=4; rel=wi-9216; }
        int blk  = rel >> 8;                // (nt*KS + ks)
        int lane = (rel >> 2) & 63;
        int pr   = rel & 3;                 // u32 slot within frag
        int nt   = blk / KS;
        int ks   = blk - nt * KS;
        int n    = nt * 32 + (lane & 31);   // output-neuron row of W^T
        int k0   = ks * 16 + (lane >> 5) * 8 + 2 * pr;
        float v0 = 0.f, v1 = 0.f;
        if (n < Nv && k0     < Kv) v0 = src[k0      * Nsrc + n];
        if (n < Nv && (k0+1) < Kv) v1 = src[(k0+1) * Nsrc + n];
        ws[WS_WT + wi] = pkbf(v0, v1);
        return;
    }
    int bi = wi - 10240;
    if (bi < 448){                          // biases -> f32 [7][64], zero padded
        int l = bi >> 6, n = bi & 63;
        const float* b; int Nv;
        if      (l==0){ b=db0; Nv=64; }
        else if (l==1){ b=db1; Nv=64; }
        else if (l==2){ b=db2; Nv=16; }
        else if (l==3){ b=cb0; Nv=64; }
        else if (l==4){ b=cb1; Nv=64; }
        else if (l==5){ b=cb2; Nv=64; }
        else          { b=cb3; Nv=3;  }
        float v = (n < Nv) ? b[n] : 0.f;
        ((float*)ws)[WS_BIAS + bi] = v;
    }
}

// ============================ fused kernel ============================

template<int NT>
__device__ __forceinline__ void loadbias(const float* blds, int bofs, int hh, f32x16 (&bi)[NT]){
    #pragma unroll
    for (int nt = 0; nt < NT; ++nt){
        #pragma unroll
        for (int s = 0; s < 4; ++s){
            f32x4 t = *(const f32x4*)(blds + bofs + nt*32 + s*8 + hh*4);
            #pragma unroll
            for (int r = 0; r < 4; ++r) bi[nt][s*4 + r] = t[r];
        }
    }
}

// One MLP layer: accn[mt][nt] = W^T * relu?(accp) + bias, all in registers.
// acc layout (32x32x16 D): col m = lane&31, row n = 32*nt + 4*(lane>>5) + (reg&3) + 8*(reg>>2)
template<int NTP, int KS, int NT, bool RELU>
__device__ __forceinline__ void advance(const u32* sm, int fb, const float* blds, int bofs,
                                        const f32x16 (&ap)[2][NTP], f32x16 (&an)[2][NT],
                                        int lane, int hh)
{
    short8 afr[NT][KS];
    #pragma unroll
    for (int nt = 0; nt < NT; ++nt)
        #pragma unroll
        for (int ks = 0; ks < KS; ++ks)
            afr[nt][ks] = *(const short8*)(sm + fb + (nt*KS + ks)*256 + lane*4);
    f32x16 bi[NT];
    loadbias<NT>(blds, bofs, hh, bi);
    #pragma unroll
    for (int mt = 0; mt < 2; ++mt){
        #pragma unroll
        for (int ks = 0; ks < KS; ++ks){
            const int tt = ks >> 1;
            const int rb = 8 * (ks & 1);
            float v[8];
            #pragma unroll
            for (int j = 0; j < 8; ++j){
                float t = ap[mt][tt][rb + j];
                v[j] = RELU ? fmaxf(t, 0.0f) : t;
            }
            u32 q0 = pkbf(v[0], v[1]);
            u32 q1 = pkbf(v[2], v[3]);
            u32 q2 = pkbf(v[4], v[5]);
            u32 q3 = pkbf(v[6], v[7]);
            pswap(q0, q2); pswap(q1, q3);
            short8 bf = mkfrag(q0, q1, q2, q3);
            #pragma unroll
            for (int nt = 0; nt < NT; ++nt)
                an[mt][nt] = MFMA(afr[nt][ks], bf, (ks == 0) ? bi[nt] : an[mt][nt], 0, 0, 0);
        }
    }
}

__launch_bounds__(256, 2)
__global__ void nerf_fused(const float* __restrict__ x, const u32* __restrict__ ws,
                           float* __restrict__ out, int npts)
{
    __shared__ u32 sm[10688];
    const int tid = threadIdx.x;
    const int p   = blockIdx.x * 256 + tid;

    float xx = 0.5f, yy = 0.5f, zz = 0.5f;
    if (p < npts){ xx = x[3*p]; yy = x[3*p+1]; zz = x[3*p+2]; }
    const float px = fmaf(xx, 0.5f, 0.5f);
    const float py = fmaf(yy, 0.5f, 0.5f);
    const float pz = fmaf(zz, 0.5f, 0.5f);

    // stage table level 0
    {
        const u32x4* tsrc = (const u32x4*)ws;
        u32x4* td = (u32x4*)sm;
        #pragma unroll
        for (int i = 0; i < 4; ++i) td[i*256 + tid] = tsrc[i*256 + tid];
    }
    __syncthreads();

    u32 flev[16];
    constexpr float RESM1[16] = {31.f,35.f,41.f,47.f,54.f,63.f,72.f,83.f,
                                 96.f,110.f,127.f,146.f,167.f,193.f,221.f,255.f};

    #pragma unroll
    for (int L = 0; L < 16; ++L){
        u32x4 st[4];
        if (L < 15){
            const u32x4* tsrc = (const u32x4*)ws + (L+1)*1024;
            #pragma unroll
            for (int i = 0; i < 4; ++i) st[i] = tsrc[i*256 + tid];
        }
        const u32* tb = sm + (L & 1) * 4096;
        const float rm = RESM1[L];
        float gx = px*rm, gy = py*rm, gz = pz*rm;
        float fx = floorf(gx), fy = floorf(gy), fz = floorf(gz);
        float wx = gx - fx, wy = gy - fy, wz = gz - fz;
        u32 ix = (u32)(int)fx, iy = (u32)(int)fy, iz = (u32)(int)fz;
        u32 hy0 = iy * 2654435761u, hy1 = hy0 + 2654435761u;
        u32 hz0 = iz * 805459861u,  hz1 = hz0 + 805459861u;
        u32 e00 = ix ^ hy0, e01 = ix ^ hy1;
        u32 e10 = (ix+1u) ^ hy0, e11 = (ix+1u) ^ hy1;
        float wx0 = 1.f-wx, wy0 = 1.f-wy, wz0 = 1.f-wz;
        float w00 = wx0*wy0, w01 = wx0*wy, w10 = wx*wy0, w11 = wx*wy;
        float f0 = 0.f, f1 = 0.f; u32 e; float wc;
        e = tb[(e00^hz0)&4095u]; wc = w00*wz0; f0 = fmaf(wc, lo16(e), f0); f1 = fmaf(wc, hi16(e), f1);
        e = tb[(e00^hz1)&4095u]; wc = w00*wz;  f0 = fmaf(wc, lo16(e), f0); f1 = fmaf(wc, hi16(e), f1);
        e = tb[(e01^hz0)&4095u]; wc = w01*wz0; f0 = fmaf(wc, lo16(e), f0); f1 = fmaf(wc, hi16(e), f1);
        e = tb[(e01^hz1)&4095u]; wc = w01*wz;  f0 = fmaf(wc, lo16(e), f0); f1 = fmaf(wc, hi16(e), f1);
        e = tb[(e10^hz0)&4095u]; wc = w10*wz0; f0 = fmaf(wc, lo16(e), f0); f1 = fmaf(wc, hi16(e), f1);
        e = tb[(e10^hz1)&4095u]; wc = w10*wz;  f0 = fmaf(wc, lo16(e), f0); f1 = fmaf(wc, hi16(e), f1);
        e = tb[(e11^hz0)&4095u]; wc = w11*wz0; f0 = fmaf(wc, lo16(e), f0); f1 = fmaf(wc, hi16(e), f1);
        e = tb[(e11^hz1)&4095u]; wc = w11*wz;  f0 = fmaf(wc, lo16(e), f0); f1 = fmaf(wc, hi16(e), f1);
        flev[L] = pkbf(f0, f1);
        if (L < 15){
            u32x4* td = (u32x4*)(sm + ((L+1) & 1) * 4096);
            #pragma unroll
            for (int i = 0; i < 4; ++i) td[i*256 + tid] = st[i];
        }
        __syncthreads();
    }

    // stage weights + bias (overwrites table buffers)
    for (int i = tid; i < 10688; i += 256) sm[i] = ws[WS_WT + i];
    __syncthreads();

    const int lane = tid & 63;
    const int hh   = lane >> 5;
    const int mcol = lane & 31;
    const int pb   = blockIdx.x * 256 + (tid >> 6) * 64;
    const float* blds = (const float*)(sm + 10240);

    // ---- L0: features (regs) -> h0 ----
    f32x16 h0[2][2];
    {
        short8 afr[2][2];
        #pragma unroll
        for (int nt = 0; nt < 2; ++nt)
            #pragma unroll
            for (int ks = 0; ks < 2; ++ks)
                afr[nt][ks] = *(const short8*)(sm + 0 + (nt*2 + ks)*256 + lane*4);
        f32x16 bi[2];
        loadbias<2>(blds, 0, hh, bi);
        #pragma unroll
        for (int ks = 0; ks < 2; ++ks){
            u32 a0 = flev[8*ks+0], a1 = flev[8*ks+1], a2 = flev[8*ks+2], a3 = flev[8*ks+3];
            u32 b0 = flev[8*ks+4], b1 = flev[8*ks+5], b2 = flev[8*ks+6], b3 = flev[8*ks+7];
            pswap(a0,b0); pswap(a1,b1); pswap(a2,b2); pswap(a3,b3);
            short8 fr0 = mkfrag(a0,a1,a2,a3);
            short8 fr1 = mkfrag(b0,b1,b2,b3);
            #pragma unroll
            for (int nt = 0; nt < 2; ++nt){
                h0[0][nt] = MFMA(afr[nt][ks], fr0, (ks==0) ? bi[nt] : h0[0][nt], 0,0,0);
                h0[1][nt] = MFMA(afr[nt][ks], fr1, (ks==0) ? bi[nt] : h0[1][nt], 0,0,0);
            }
        }
    }

    f32x16 h1[2][2]; advance<2,4,2,true >(sm, 1024, blds, 64,  h0, h1, lane, hh);
    f32x16 h2[2][1]; advance<2,4,1,true >(sm, 3072, blds, 128, h1, h2, lane, hh);

    // sigma = exp(d2[:,0]) from the raw f32 accumulator (n=0 -> hh==0, reg 0)
    if (hh == 0){
        #pragma unroll
        for (int mt = 0; mt < 2; ++mt){
            int gp = pb + 32*mt + mcol;
            if (gp < npts) out[3*npts + gp] = __expf(h2[mt][0][0]);
        }
    }

    f32x16 h3[2][2]; advance<1,2,2,false>(sm, 4096, blds, 192, h2, h3, lane, hh);
    f32x16 h4[2][2]; advance<2,4,2,true >(sm, 5120, blds, 256, h3, h4, lane, hh);
    f32x16 h5[2][2]; advance<2,4,2,true >(sm, 7168, blds, 320, h4, h5, lane, hh);
    f32x16 h6[2][1]; advance<2,4,1,true >(sm, 9216, blds, 384, h5, h6, lane, hh);

    if (hh == 0){
        #pragma unroll
        for (int mt = 0; mt < 2; ++mt){
            int gp = pb + 32*mt + mcol;
            if (gp < npts){
                float c0 = h6[mt][0][0], c1 = h6[mt][0][1], c2 = h6[mt][0][2];
                out[gp*3+0] = 1.f/(1.f + __expf(-c0));
                out[gp*3+1] = 1.f/(1.f + __expf(-c1));
                out[gp*3+2] = 1.f/(1.f + __expf(-c2));
            }
        }
    }
}

extern "C" void kernel_launch(void* const* d_in, const int* in_sizes, int n_in,
                              void* d_out, int out_size, void* d_ws, size_t ws_size,
                              hipStream_t stream)
{
    (void)n_in; (void)out_size; (void)ws_size;   // needs ws_size >= 304896 B
    const float* x      = (const float*)d_in[0];
    const float* tables = (const float*)d_in[1];
    const float* dW0 = (const float*)d_in[2];  const float* db0 = (const float*)d_in[3];
    const float* dW1 = (const float*)d_in[4];  const float* db1 = (const float*)d_in[5];
    const float* dW2 = (const float*)d_in[6];  const float* db2 = (const float*)d_in[7];
    const float* cW0 = (const float*)d_in[8];  const float* cb0 = (const float*)d_in[9];
    const float* cW1 = (const float*)d_in[10]; const float* cb1 = (const float*)d_in[11];
    const float* cW2 = (const float*)d_in[12]; const float* cb2 = (const float*)d_in[13];
    const float* cW3 = (const float*)d_in[14]; const float* cb3 = (const float*)d_in[15];
    u32* ws    = (u32*)d_ws;
    float* out = (float*)d_out;
    int npts = in_sizes[0] / 3;

    prep_kernel<<<298, 256, 0, stream>>>(tables, dW0,dW1,dW2,cW0,cW1,cW2,cW3,
                                         db0,db1,db2,cb0,cb1,cb2,cb3, ws);
    int nb = (npts + 255) / 256;
    nerf_fused<<<nb, 256, 0, stream>>>(x, ws, out, npts);
}